// Round 15
// baseline (179.493 us; speedup 1.0000x reference)
//
#include <hip/hip_runtime.h>
#include <hip/hip_bf16.h>

// Sizes (fixed by the problem)
#define HDIM 512
#define BB 32
#define SS 4096
#define TR 64                  // rows per chunk
#define CPB 8                  // chunks per block
#define NCH 64                 // partials per b (8 blocks x 8 chunks)
#define NBLK 256               // 1 block per CU

typedef __attribute__((ext_vector_type(8))) short short8;   // 8 x bf16
typedef __attribute__((ext_vector_type(4))) float f32x4;

// Workspace layout (bytes)
#define WS_QB    0                        // 32*512*4 = 65536
#define WS_WRBF  65536                    // 512*512*2 = 524288 (fragment-major)
#define WS_PM    (65536+524288)           // 2048*4 (16KB region)
#define WS_PD    (WS_PM+16384)            // 2048*4 (16KB region)
#define WS_PRB   (WS_PD+16384)            // 2048*512*4 = 4MB (r-domain partials)

__device__ __forceinline__ unsigned cvt_pk_bf16(float lo, float hi){
  unsigned r;
  asm("v_cvt_pk_bf16_f32 %0, %1, %2" : "=v"(r) : "v"(lo), "v"(hi));
  return r;
}

// ---------------- K1: prep (fused) ----------------
// blocks 0..127 : fragment-major bf16 Wr (frag = one contiguous 1KB wave load)
// blocks 128..159: qb[b,h] = bq[h] + br[h] + query[b,:] . Wq[h,:]
__global__ __launch_bounds__(256) void k_prep(const float* __restrict__ Wr,
                                              unsigned short* __restrict__ wrbF,
                                              const float* __restrict__ query,
                                              const float* __restrict__ Wq,
                                              const float* __restrict__ bq,
                                              const float* __restrict__ br,
                                              float* __restrict__ qb){
  int t = threadIdx.x;
  if (blockIdx.x < 128){
    int gid = blockIdx.x*256 + t;        // [0, 32768)
    int lane = gid & 63;
    int tile = gid >> 6;                 // [0,512): kt = tile&15, t16 = tile>>4
    int kt = tile & 15, t16 = tile >> 4;
    int col = t16*16 + (lane & 15);
    int k0  = kt*32 + (lane >> 4)*8;
    const float* src = Wr + (size_t)col*HDIM + k0;
    f32x4 v0 = *(const f32x4*)(src);
    f32x4 v1 = *(const f32x4*)(src + 4);
    uint4 o;
    o.x = cvt_pk_bf16(v0.x, v0.y);
    o.y = cvt_pk_bf16(v0.z, v0.w);
    o.z = cvt_pk_bf16(v1.x, v1.y);
    o.w = cvt_pk_bf16(v1.z, v1.w);
    *(uint4*)(wrbF + (size_t)gid*8) = o;
  } else {
    __shared__ __align__(16) float sq[HDIM];
    int b = blockIdx.x - 128;
    sq[t] = query[b*HDIM + t];
    sq[t+256] = query[b*HDIM + t + 256];
    __syncthreads();
    const f32x4* sq4 = (const f32x4*)sq;
    for (int hh = 0; hh < 2; ++hh){
      int h = t + hh*256;
      const f32x4* w4 = (const f32x4*)(Wq + (size_t)h*HDIM);
      float acc = bq[h] + br[h];
      #pragma unroll 4
      for (int k = 0; k < HDIM/4; ++k){
        f32x4 w = w4[k]; f32x4 q = sq4[k];
        acc += w.x*q.x + w.y*q.y + w.z*q.z + w.w*q.w;
      }
      qb[b*HDIM + h] = acc;
    }
  }
}

// ---------------- K2: main fused kernel (wave-specialized, 768 threads) ----
// 256 blocks x 768 thr (12 waves), 1 block/CU (137KB LDS) -> 3 waves/EU.
// amdgpu_waves_per_eu(3,3) pins that occupancy so the allocator gets the
// full ~170-reg budget (R14 lesson: without it, 128-budget -> 40MB spill).
// Waves 0..7  (consumers): R11's GEMM+logits+prb for chunk c from sA[c&1].
// Waves 8..11 (producers): stage chunk c+1 f32->bf16 into sA[(c+1)&1]
//                          concurrently with the consumers' GEMM.
// Wave 8 does the per-chunk softmax between the two barriers.
__global__ __launch_bounds__(768)
__attribute__((amdgpu_waves_per_eu(3, 3)))
void k_main(const float* __restrict__ ref,
            const unsigned short* __restrict__ wrbF,
            const float* __restrict__ qb,
            const float* __restrict__ V,
            float* __restrict__ pm,
            float* __restrict__ pd,
            float* __restrict__ prb){
  int bid = blockIdx.x;
  int b = bid >> 3;                 // 8 blocks per b
  int grp = bid & 7;                // rows [grp*512, grp*512+512)
  int tid = threadIdx.x;
  int w = tid >> 6, lane = tid & 63;
  int lo16 = lane & 15, g = lane >> 4;

  __shared__ __align__(16) unsigned short sA[2][TR*HDIM]; // 2 x 64KB swizzled bf16
  __shared__ __align__(16) float sQb[HDIM];
  __shared__ __align__(16) float sV[HDIM];
  __shared__ float sLog[8][TR];
  __shared__ __align__(16) float sE[TR];

  if (tid < HDIM){
    sQb[tid] = qb[b*HDIM + tid];
    sV[tid]  = V[tid];
  }

  const float* refRows = ref + ((size_t)b*SS + (size_t)grp*(TR*CPB))*HDIM;
  const float C2L2E = 2.8853900817779268f;   // 2*log2(e)

  // ---- prologue: producer waves stage chunk 0 into sA[0] ----
  if (w >= 8){
    int tp = tid - 512;               // [0,256)
    const f32x4* s4 = (const f32x4*)refRows + tp;
    char* dst = (char*)sA[0];
    #pragma unroll
    for (int p = 0; p < 8; ++p){
      f32x4 R[4];
      #pragma unroll
      for (int i = 0; i < 4; ++i) R[i] = s4[p*1024 + 256*i];
      #pragma unroll
      for (int i = 0; i < 4; ++i){
        int idx = tp + 256*i + p*1024;
        int row = idx >> 7, c4 = idx & 127;
        uint2 o;
        o.x = cvt_pk_bf16(R[i].x, R[i].y);
        o.y = cvt_pk_bf16(R[i].z, R[i].w);
        unsigned byte = (unsigned)(row*1024) + (((unsigned)c4*8) ^ ((unsigned)(row & 7) << 4));
        *(uint2*)(dst + byte) = o;
      }
    }
  }
  __syncthreads();

  for (int c = 0; c < CPB; ++c){
    const char* cur = (const char*)sA[c & 1];
    int cg = grp*CPB + c;
    f32x4 acc[4][4];

    if (w < 8){
      // ===== CONSUMER: GEMM chunk c, cols [w*64, w*64+64) — R11 verbatim ====
      unsigned baseA = (unsigned)(lo16*1024) + (((unsigned)g*16) ^ ((unsigned)(lo16 & 3) << 4));
      unsigned bsel  = (unsigned)((lo16 >> 2) & 1) * 64u;
      const char* pAe = cur + baseA + bsel;        // even kt: + kt*64
      const char* pAo = cur + baseA - bsel + 64;   // odd kt:  + (kt-1)*64
      const short8* wfp = (const short8*)wrbF + ((size_t)(w*4)*16*64 + lane);

      #pragma unroll
      for (int m = 0; m < 4; ++m)
        #pragma unroll
        for (int n = 0; n < 4; ++n)
          acc[m][n] = (f32x4){0.f, 0.f, 0.f, 0.f};

      #pragma unroll 4
      for (int kt = 0; kt < 16; ++kt){
        short8 af[4];
        #pragma unroll
        for (int m = 0; m < 4; ++m){
          if (kt & 1)
            af[m] = *(const short8*)(pAo + (m*16384 + (kt-1)*64));
          else
            af[m] = *(const short8*)(pAe + (m*16384 + kt*64));
        }
        short8 bfr[4];
        #pragma unroll
        for (int n = 0; n < 4; ++n)
          bfr[n] = wfp[(size_t)n*1024 + kt*64];
        #pragma unroll
        for (int m = 0; m < 4; ++m)
          #pragma unroll
          for (int n = 0; n < 4; ++n)
            acc[m][n] = __builtin_amdgcn_mfma_f32_16x16x32_bf16(af[m], bfr[n], acc[m][n], 0, 0, 0);
      }

      // logits epilogue: D-layout col=w*64+n*16+lo16, row=16m+4g+r
      float lacc[4][4];
      #pragma unroll
      for (int m = 0; m < 4; ++m)
        #pragma unroll
        for (int r = 0; r < 4; ++r)
          lacc[m][r] = 0.f;
      float SV = 0.f;
      #pragma unroll
      for (int n = 0; n < 4; ++n){
        int col = w*64 + n*16 + lo16;
        float qc  = C2L2E * sQb[col];
        float vv  = sV[col];
        float vv2 = -2.f * vv;
        SV += vv;
        #pragma unroll
        for (int m = 0; m < 4; ++m)
          #pragma unroll
          for (int r = 0; r < 4; ++r){
            float e  = __builtin_amdgcn_exp2f(__builtin_fmaf(C2L2E, acc[m][n][r], qc));
            float rc = __builtin_amdgcn_rcpf(1.f + e);
            lacc[m][r] = __builtin_fmaf(vv2, rc, lacc[m][r]);
          }
      }
      #pragma unroll
      for (int m = 0; m < 4; ++m)
        #pragma unroll
        for (int r = 0; r < 4; ++r){
          float v = lacc[m][r] + SV;
          v += __shfl_xor(v, 1); v += __shfl_xor(v, 2);
          v += __shfl_xor(v, 4); v += __shfl_xor(v, 8);
          lacc[m][r] = v;
        }
      if (lo16 == 0){
        #pragma unroll
        for (int m = 0; m < 4; ++m)
          #pragma unroll
          for (int r = 0; r < 4; ++r)
            sLog[w][16*m + 4*g + r] = lacc[m][r];
      }
    } else {
      // ===== PRODUCER: stage chunk c+1 into sA[(c+1)&1] ======================
      if (c + 1 < CPB){
        int tp = tid - 512;               // [0,256)
        const f32x4* s4 = (const f32x4*)(refRows + (size_t)(c+1)*TR*HDIM) + tp;
        char* dst = (char*)sA[(c+1) & 1];
        #pragma unroll
        for (int p = 0; p < 8; ++p){
          f32x4 R[4];
          #pragma unroll
          for (int i = 0; i < 4; ++i) R[i] = s4[p*1024 + 256*i];
          #pragma unroll
          for (int i = 0; i < 4; ++i){
            int idx = tp + 256*i + p*1024;
            int row = idx >> 7, c4 = idx & 127;
            uint2 o;
            o.x = cvt_pk_bf16(R[i].x, R[i].y);
            o.y = cvt_pk_bf16(R[i].z, R[i].w);
            unsigned byte = (unsigned)(row*1024) + (((unsigned)c4*8) ^ ((unsigned)(row & 7) << 4));
            *(uint2*)(dst + byte) = o;
          }
        }
      }
    }
    __syncthreads();   // (1) sLog ready; next buffer staged

    // ---- per-chunk softmax (wave 8) ----
    if (w == 8){
      float l = sLog[0][lane] + sLog[1][lane] + sLog[2][lane] + sLog[3][lane]
              + sLog[4][lane] + sLog[5][lane] + sLog[6][lane] + sLog[7][lane];
      float mx = l;
      mx = fmaxf(mx, __shfl_xor(mx, 1));  mx = fmaxf(mx, __shfl_xor(mx, 2));
      mx = fmaxf(mx, __shfl_xor(mx, 4));  mx = fmaxf(mx, __shfl_xor(mx, 8));
      mx = fmaxf(mx, __shfl_xor(mx, 16)); mx = fmaxf(mx, __shfl_xor(mx, 32));
      float e = __expf(l - mx);
      float d = e;
      d += __shfl_xor(d, 1); d += __shfl_xor(d, 2); d += __shfl_xor(d, 4);
      d += __shfl_xor(d, 8); d += __shfl_xor(d, 16); d += __shfl_xor(d, 32);
      sE[lane] = e;
      if (lane == 0){ pm[b*NCH + cg] = mx; pd[b*NCH + cg] = d; }
    }
    __syncthreads();   // (2) sE ready

    // ---- consumer: r-domain partial from in-register acc (R11 verbatim) ----
    if (w < 8){
      f32x4 e4[4];
      #pragma unroll
      for (int m = 0; m < 4; ++m)
        e4[m] = *(const f32x4*)&sE[16*m + 4*g];     // rows 16m+4g+0..3
      #pragma unroll
      for (int n = 0; n < 4; ++n){
        float rb = 0.f;
        #pragma unroll
        for (int m = 0; m < 4; ++m)
          #pragma unroll
          for (int r = 0; r < 4; ++r)
            rb = __builtin_fmaf(e4[m][r], acc[m][n][r], rb);
        rb += __shfl_xor(rb, 16);
        rb += __shfl_xor(rb, 32);     // fold the 4 g-groups (rows)
        if (g == 0)
          prb[((size_t)(b*NCH + cg))*HDIM + w*64 + n*16 + lo16] = rb;
      }
    }
    // no 3rd barrier needed: next iter's producer writes sA[(c+2)&1] which
    // consumers finished reading before barrier (1); prb/softmax touch only
    // sE/sLog which are rewritten only after the next barrier pair.
  }
}

// ---------------- K3: combine 64 r-domain partials per b, add br ----------------
__global__ __launch_bounds__(256) void k_final(const float* __restrict__ br,
                                               const float* __restrict__ pm,
                                               const float* __restrict__ pd,
                                               const float* __restrict__ prb,
                                               float* __restrict__ out){
  int b = blockIdx.x, t = threadIdx.x, lane = t & 63, w = t >> 6;
  __shared__ float sSc[NCH];
  __shared__ float sMD0;

  if (w == 0){
    float m = pm[b*NCH + lane];
    float mx = m;
    mx = fmaxf(mx, __shfl_xor(mx, 1));  mx = fmaxf(mx, __shfl_xor(mx, 2));
    mx = fmaxf(mx, __shfl_xor(mx, 4));  mx = fmaxf(mx, __shfl_xor(mx, 8));
    mx = fmaxf(mx, __shfl_xor(mx, 16)); mx = fmaxf(mx, __shfl_xor(mx, 32));
    float sc = __expf(m - mx);
    float d = sc * pd[b*NCH + lane];
    d += __shfl_xor(d, 1); d += __shfl_xor(d, 2); d += __shfl_xor(d, 4);
    d += __shfl_xor(d, 8); d += __shfl_xor(d, 16); d += __shfl_xor(d, 32);
    sSc[lane] = sc;
    if (lane == 0) sMD0 = d;
  }
  __syncthreads();

  float inv = 1.f / sMD0;
  float u0 = 0.f, u1 = 0.f;
  for (int c = 0; c < NCH; ++c){
    float sc = sSc[c];
    const float* p = prb + ((size_t)(b*NCH + c))*HDIM;
    u0 += sc * p[t];
    u1 += sc * p[t+256];
  }
  out[b*HDIM + t]       = u0 * inv + br[t];
  out[b*HDIM + t + 256] = u1 * inv + br[t + 256];
}

extern "C" void kernel_launch(void* const* d_in, const int* in_sizes, int n_in,
                              void* d_out, int out_size, void* d_ws, size_t ws_size,
                              hipStream_t stream){
  const float* query = (const float*)d_in[0];
  const float* ref   = (const float*)d_in[1];
  const float* Wq    = (const float*)d_in[2];
  const float* bq    = (const float*)d_in[3];
  const float* Wr    = (const float*)d_in[4];
  const float* br    = (const float*)d_in[5];
  const float* V     = (const float*)d_in[6];
  char* ws = (char*)d_ws;
  float*          qbv  = (float*)(ws + WS_QB);
  unsigned short* wrbF = (unsigned short*)(ws + WS_WRBF);
  float*          pm   = (float*)(ws + WS_PM);
  float*          pd   = (float*)(ws + WS_PD);
  float*          prb  = (float*)(ws + WS_PRB);
  float* out = (float*)d_out;

  k_prep<<<dim3(160), dim3(256), 0, stream>>>(Wr, wrbF, query, Wq, bq, br, qbv);
  k_main<<<dim3(NBLK), dim3(768), 0, stream>>>(ref, wrbF, qbv, V, pm, pd, prb);
  k_final<<<dim3(BB), dim3(256), 0, stream>>>(br, pm, pd, prb, out);
}

// Round 16
// 154.873 us; speedup vs baseline: 1.1590x; 1.1590x over previous
//
#include <hip/hip_runtime.h>
#include <hip/hip_bf16.h>

// Sizes (fixed by the problem)
#define HDIM 512
#define BB 32
#define SS 4096
#define NBLK 256               // 1 block per CU
#define NCH 64                 // partials per b (8 blocks x 8 tiles)

typedef __attribute__((ext_vector_type(8))) short short8;   // 8 x bf16
typedef __attribute__((ext_vector_type(4))) float f32x4;

// Workspace layout (bytes)
#define WS_QB    0                        // 32*512*4 = 65536
#define WS_WRBF  65536                    // 512*512*2 = 524288 (fragment-major)
#define WS_PM    (65536+524288)           // 2048*4 (16KB region)
#define WS_PD    (WS_PM+16384)            // 2048*4 (16KB region)
#define WS_PRB   (WS_PD+16384)            // 2048*512*4 = 4MB (r-domain partials)

__device__ __forceinline__ unsigned cvt_pk_bf16(float lo, float hi){
  unsigned r;
  asm("v_cvt_pk_bf16_f32 %0, %1, %2" : "=v"(r) : "v"(lo), "v"(hi));
  return r;
}

// LDS-only barrier: waits LDS ops, leaves global_load_lds DMAs (vmcnt) in flight.
__device__ __forceinline__ void lds_barrier(){
  __builtin_amdgcn_sched_barrier(0);
  asm volatile("s_waitcnt lgkmcnt(0)" ::: "memory");
  __builtin_amdgcn_s_barrier();
  __builtin_amdgcn_sched_barrier(0);
}

__device__ __forceinline__ void wait_vm0(){
  asm volatile("s_waitcnt vmcnt(0)" ::: "memory");
  __builtin_amdgcn_sched_barrier(0);
}

// async DMA one 64x128-f32 quarter (32KB) into linear LDS [64][128] f32.
// Zero VGPR staging (R5-proven). refB = block's first row (512 rows).
__device__ __forceinline__ void dma_quarter(const char* refB, int Q, float* fdst,
                                            int w, int lane){
  int T = Q >> 2, q = Q & 3;
  const char* gbase = refB + (size_t)T*64*2048 + q*512;
  #pragma unroll
  for (int j = 0; j < 2; ++j){
    int rr = 2*(j*16 + w) + (lane >> 5);
    const char* gsrc = gbase + (size_t)rr*2048 + (size_t)(lane & 31)*16;
    char* l = (char*)fdst + (j*16 + w)*1024;   // wave-uniform; HW adds lane*16
    __builtin_amdgcn_global_load_lds((const __attribute__((address_space(1))) void*)gsrc,
                                     (__attribute__((address_space(3))) void*)l, 16, 0, 0);
  }
}

// convert one quarter: f32 linear LDS -> bf16 swizzled LDS.
// bf16 layout: byte = row*256 + ((2k) ^ ((row&7)<<4))  (R11's conflict-free swizzle)
__device__ __forceinline__ void convert_quarter(const float* fsrc, unsigned short* bdst,
                                                int w, int lane){
  #pragma unroll
  for (int j = 0; j < 2; ++j){
    int off = (j*16 + w)*1024 + lane*16;
    f32x4 v = *(const f32x4*)((const char*)fsrc + off);
    int e0 = off >> 2;
    int row = e0 >> 7, k0 = e0 & 127;
    uint2 o;
    o.x = cvt_pk_bf16(v.x, v.y);
    o.y = cvt_pk_bf16(v.z, v.w);
    unsigned byte = (unsigned)(row*256) + (((unsigned)(2*k0)) ^ ((unsigned)(row & 7) << 4));
    *(uint2*)((char*)bdst + byte) = o;
  }
}

// ---------------- K1: prep (fused) ----------------
// blocks 0..127 : fragment-major bf16 Wr (frag = one contiguous 1KB wave load)
// blocks 128..159: qb[b,h] = bq[h] + br[h] + query[b,:] . Wq[h,:]
__global__ __launch_bounds__(256) void k_prep(const float* __restrict__ Wr,
                                              unsigned short* __restrict__ wrbF,
                                              const float* __restrict__ query,
                                              const float* __restrict__ Wq,
                                              const float* __restrict__ bq,
                                              const float* __restrict__ br,
                                              float* __restrict__ qb){
  int t = threadIdx.x;
  if (blockIdx.x < 128){
    int gid = blockIdx.x*256 + t;        // [0, 32768)
    int lane = gid & 63;
    int tile = gid >> 6;                 // [0,512): kt = tile&15, t16 = tile>>4
    int kt = tile & 15, t16 = tile >> 4;
    int col = t16*16 + (lane & 15);
    int k0  = kt*32 + (lane >> 4)*8;
    const float* src = Wr + (size_t)col*HDIM + k0;
    f32x4 v0 = *(const f32x4*)(src);
    f32x4 v1 = *(const f32x4*)(src + 4);
    uint4 o;
    o.x = cvt_pk_bf16(v0.x, v0.y);
    o.y = cvt_pk_bf16(v0.z, v0.w);
    o.z = cvt_pk_bf16(v1.x, v1.y);
    o.w = cvt_pk_bf16(v1.z, v1.w);
    *(uint4*)(wrbF + (size_t)gid*8) = o;
  } else {
    __shared__ __align__(16) float sq[HDIM];
    int b = blockIdx.x - 128;
    sq[t] = query[b*HDIM + t];
    sq[t+256] = query[b*HDIM + t + 256];
    __syncthreads();
    const f32x4* sq4 = (const f32x4*)sq;
    for (int hh = 0; hh < 2; ++hh){
      int h = t + hh*256;
      const f32x4* w4 = (const f32x4*)(Wq + (size_t)h*HDIM);
      float acc = bq[h] + br[h];
      #pragma unroll 4
      for (int k = 0; k < HDIM/4; ++k){
        f32x4 w = w4[k]; f32x4 q = sq4[k];
        acc += w.x*q.x + w.y*q.y + w.z*q.z + w.w*q.w;
      }
      qb[b*HDIM + h] = acc;
    }
  }
}

// ---------------- K2: main fused kernel (DMA-pipelined, uniform waves) ----
// 256 blocks x 1024 thr (16 waves, 4/SIMD), 1 block/CU, ~120KB LDS.
// Block owns 512 rows = 8 tiles x 4 K-quarters. Pipeline per quarter:
//   vmcnt(0) [DMA(Q+1) done] -> lgkm-barrier -> issue DMA(Q+2) ->
//   convert(Q+1) f32->bf16 -> GEMM(Q) from bf16 ring (3 slots).
// DMAs cross all barriers (lgkm-only). acc[4][2]/wave over tile (K=512).
// Tile end: logits epilogue -> softmax -> r-domain partial (no u-pass).
// R5-proven skeleton (no staging regs, no spill @1024thr) + R6 fragment-B.
__global__ __launch_bounds__(1024)
__attribute__((amdgpu_waves_per_eu(4, 4)))
void k_main(const float* __restrict__ ref,
            const unsigned short* __restrict__ wrbF,
            const float* __restrict__ qb,
            const float* __restrict__ V,
            float* __restrict__ pm,
            float* __restrict__ pd,
            float* __restrict__ prb){
  int bid = blockIdx.x;
  int b = bid >> 3;                 // 8 blocks per b
  int grp = bid & 7;                // rows [grp*512, grp*512+512)
  int tid = threadIdx.x;
  int w = tid >> 6, lane = tid & 63;
  int lo16 = lane & 15, g = lane >> 4;

  __shared__ __align__(16) unsigned short sB[3][64*128]; // 3 x 16KB bf16 ring
  __shared__ __align__(16) float sF[2][64*128];          // 2 x 32KB f32 DMA bufs
  __shared__ __align__(16) float sQb[HDIM];
  __shared__ __align__(16) float sV[HDIM];
  __shared__ float sLog[16][64];
  __shared__ __align__(16) float sE[64];

  if (tid < HDIM){
    sQb[tid] = qb[b*HDIM + tid];
    sV[tid]  = V[tid];
  }

  const char* refB = (const char*)(ref + ((size_t)b*SS + (size_t)grp*512)*HDIM);
  const float C2L2E = 2.8853900817779268f;   // 2*log2(e)

  // ---- prologue ----
  dma_quarter(refB, 0, sF[0], w, lane);
  wait_vm0();
  lds_barrier();
  convert_quarter(sF[0], sB[0], w, lane);
  dma_quarter(refB, 1, sF[1], w, lane);

  f32x4 acc[4][2];

  for (int Q = 0; Q < 32; ++Q){
    int q = Q & 3;

    wait_vm0();        // DMA(Q+1) complete (issued last iteration)
    lds_barrier();     // converts + DMA visible block-wide

    if (Q + 2 < 32) dma_quarter(refB, Q+2, sF[Q & 1], w, lane);     // (Q+2)&1 == Q&1
    if (Q + 1 < 32) convert_quarter(sF[(Q+1) & 1], sB[(Q+1) % 3], w, lane);

    // ---- GEMM quarter Q: wave covers cols [(w*2)*16, (w*2+2)*16), rows 0..63
    if (q == 0){
      #pragma unroll
      for (int m = 0; m < 4; ++m)
        #pragma unroll
        for (int n = 0; n < 2; ++n)
          acc[m][n] = (f32x4){0.f, 0.f, 0.f, 0.f};
    }
    {
      const char* bb = (const char*)sB[Q % 3];
      unsigned baseA = (unsigned)(lo16*256) + (((unsigned)(g*16)) ^ ((unsigned)(lo16 & 3) << 4));
      unsigned bsel  = (unsigned)((lo16 >> 2) & 1) * 64u;
      const char* pAe = bb + baseA + bsel;        // even ktl: + ktl*64
      const char* pAo = bb + baseA - bsel + 64;   // odd ktl:  + (ktl-1)*64
      const short8* wf0 = (const short8*)wrbF + ((size_t)((w*2+0)*16 + q*4)*64 + lane);
      const short8* wf1 = (const short8*)wrbF + ((size_t)((w*2+1)*16 + q*4)*64 + lane);

      #pragma unroll
      for (int ktl = 0; ktl < 4; ++ktl){
        short8 af[4];
        #pragma unroll
        for (int m = 0; m < 4; ++m){
          if (ktl & 1)
            af[m] = *(const short8*)(pAo + (m*4096 + (ktl-1)*64));
          else
            af[m] = *(const short8*)(pAe + (m*4096 + ktl*64));
        }
        short8 b0 = wf0[ktl*64];
        short8 b1 = wf1[ktl*64];
        #pragma unroll
        for (int m = 0; m < 4; ++m){
          acc[m][0] = __builtin_amdgcn_mfma_f32_16x16x32_bf16(af[m], b0, acc[m][0], 0, 0, 0);
          acc[m][1] = __builtin_amdgcn_mfma_f32_16x16x32_bf16(af[m], b1, acc[m][1], 0, 0, 0);
        }
      }
    }

    if (q == 3){
      int T = Q >> 2;
      int cg = grp*8 + T;
      // ---- logits epilogue: D-layout col=(w*2+n)*16+lo16, row=16m+4g+r ----
      float lacc[4][4];
      #pragma unroll
      for (int m = 0; m < 4; ++m)
        #pragma unroll
        for (int r = 0; r < 4; ++r)
          lacc[m][r] = 0.f;
      float SV = 0.f;
      #pragma unroll
      for (int n = 0; n < 2; ++n){
        int col = (w*2 + n)*16 + lo16;
        float qc  = C2L2E * sQb[col];
        float vv  = sV[col];
        float vv2 = -2.f * vv;
        SV += vv;
        #pragma unroll
        for (int m = 0; m < 4; ++m)
          #pragma unroll
          for (int r = 0; r < 4; ++r){
            float e  = __builtin_amdgcn_exp2f(__builtin_fmaf(C2L2E, acc[m][n][r], qc));
            float rc = __builtin_amdgcn_rcpf(1.f + e);
            lacc[m][r] = __builtin_fmaf(vv2, rc, lacc[m][r]);
          }
      }
      #pragma unroll
      for (int m = 0; m < 4; ++m)
        #pragma unroll
        for (int r = 0; r < 4; ++r){
          float v = lacc[m][r] + SV;
          v += __shfl_xor(v, 1); v += __shfl_xor(v, 2);
          v += __shfl_xor(v, 4); v += __shfl_xor(v, 8);
          lacc[m][r] = v;
        }
      if (lo16 == 0){
        #pragma unroll
        for (int m = 0; m < 4; ++m)
          #pragma unroll
          for (int r = 0; r < 4; ++r)
            sLog[w][16*m + 4*g + r] = lacc[m][r];
      }
      lds_barrier();

      // ---- tile softmax (wave 0; 64 lanes = 64 rows) ----
      if (w == 0){
        float l = 0.f;
        #pragma unroll
        for (int ww = 0; ww < 16; ++ww) l += sLog[ww][lane];
        float mx = l;
        mx = fmaxf(mx, __shfl_xor(mx, 1));  mx = fmaxf(mx, __shfl_xor(mx, 2));
        mx = fmaxf(mx, __shfl_xor(mx, 4));  mx = fmaxf(mx, __shfl_xor(mx, 8));
        mx = fmaxf(mx, __shfl_xor(mx, 16)); mx = fmaxf(mx, __shfl_xor(mx, 32));
        float e = __expf(l - mx);
        float d = e;
        d += __shfl_xor(d, 1); d += __shfl_xor(d, 2); d += __shfl_xor(d, 4);
        d += __shfl_xor(d, 8); d += __shfl_xor(d, 16); d += __shfl_xor(d, 32);
        sE[lane] = e;
        if (lane == 0){ pm[b*NCH + cg] = mx; pd[b*NCH + cg] = d; }
      }
      lds_barrier();

      // ---- r-domain partial from in-register acc ----
      {
        f32x4 e4[4];
        #pragma unroll
        for (int m = 0; m < 4; ++m)
          e4[m] = *(const f32x4*)&sE[16*m + 4*g];     // rows 16m+4g+0..3
        #pragma unroll
        for (int n = 0; n < 2; ++n){
          float rb = 0.f;
          #pragma unroll
          for (int m = 0; m < 4; ++m)
            #pragma unroll
            for (int r = 0; r < 4; ++r)
              rb = __builtin_fmaf(e4[m][r], acc[m][n][r], rb);
          rb += __shfl_xor(rb, 16);
          rb += __shfl_xor(rb, 32);     // fold the 4 g-groups (rows)
          if (g == 0)
            prb[((size_t)(b*NCH + cg))*HDIM + (w*2 + n)*16 + lo16] = rb;
        }
      }
      // sE/sLog reused only after the next iteration's lds_barrier.
    }
  }
}

// ---------------- K3: combine 64 r-domain partials per b, add br ----------------
__global__ __launch_bounds__(256) void k_final(const float* __restrict__ br,
                                               const float* __restrict__ pm,
                                               const float* __restrict__ pd,
                                               const float* __restrict__ prb,
                                               float* __restrict__ out){
  int b = blockIdx.x, t = threadIdx.x, lane = t & 63, w = t >> 6;
  __shared__ float sSc[NCH];
  __shared__ float sMD0;

  if (w == 0){
    float m = pm[b*NCH + lane];
    float mx = m;
    mx = fmaxf(mx, __shfl_xor(mx, 1));  mx = fmaxf(mx, __shfl_xor(mx, 2));
    mx = fmaxf(mx, __shfl_xor(mx, 4));  mx = fmaxf(mx, __shfl_xor(mx, 8));
    mx = fmaxf(mx, __shfl_xor(mx, 16)); mx = fmaxf(mx, __shfl_xor(mx, 32));
    float sc = __expf(m - mx);
    float d = sc * pd[b*NCH + lane];
    d += __shfl_xor(d, 1); d += __shfl_xor(d, 2); d += __shfl_xor(d, 4);
    d += __shfl_xor(d, 8); d += __shfl_xor(d, 16); d += __shfl_xor(d, 32);
    sSc[lane] = sc;
    if (lane == 0) sMD0 = d;
  }
  __syncthreads();

  float inv = 1.f / sMD0;
  float u0 = 0.f, u1 = 0.f;
  for (int c = 0; c < NCH; ++c){
    float sc = sSc[c];
    const float* p = prb + ((size_t)(b*NCH + c))*HDIM;
    u0 += sc * p[t];
    u1 += sc * p[t+256];
  }
  out[b*HDIM + t]       = u0 * inv + br[t];
  out[b*HDIM + t + 256] = u1 * inv + br[t + 256];
}

extern "C" void kernel_launch(void* const* d_in, const int* in_sizes, int n_in,
                              void* d_out, int out_size, void* d_ws, size_t ws_size,
                              hipStream_t stream){
  const float* query = (const float*)d_in[0];
  const float* ref   = (const float*)d_in[1];
  const float* Wq    = (const float*)d_in[2];
  const float* bq    = (const float*)d_in[3];
  const float* Wr    = (const float*)d_in[4];
  const float* br    = (const float*)d_in[5];
  const float* V     = (const float*)d_in[6];
  char* ws = (char*)d_ws;
  float*          qbv  = (float*)(ws + WS_QB);
  unsigned short* wrbF = (unsigned short*)(ws + WS_WRBF);
  float*          pm   = (float*)(ws + WS_PM);
  float*          pd   = (float*)(ws + WS_PD);
  float*          prb  = (float*)(ws + WS_PRB);
  float* out = (float*)d_out;

  k_prep<<<dim3(160), dim3(256), 0, stream>>>(Wr, wrbF, query, Wq, bq, br, qbv);
  k_main<<<dim3(NBLK), dim3(1024), 0, stream>>>(ref, wrbF, qbv, V, pm, pd, prb);
  k_final<<<dim3(BB), dim3(256), 0, stream>>>(br, pm, pd, prb, out);
}

// Round 17
// 136.707 us; speedup vs baseline: 1.3130x; 1.1329x over previous
//
#include <hip/hip_runtime.h>
#include <hip/hip_bf16.h>

// Sizes (fixed by the problem)
#define HDIM 512
#define BB 32
#define SS 4096
#define TR 64                  // rows per block
#define NCH (SS/TR)            // 64 chunks per b
#define NBLK (BB*NCH)          // 2048 blocks

typedef __attribute__((ext_vector_type(8))) short short8;   // 8 x bf16
typedef __attribute__((ext_vector_type(4))) float f32x4;

// Workspace layout (bytes)
#define WS_QB    0                        // 32*512*4 = 65536
#define WS_WRBF  65536                    // 512*512*2 = 524288 (fragment-major)
#define WS_PM    (65536+524288)           // 2048*4 (16KB region)
#define WS_PD    (WS_PM+16384)            // 2048*4 (16KB region)
#define WS_PRB   (WS_PD+16384)            // 2048*512*4 = 4MB (r-domain partials)

__device__ __forceinline__ unsigned cvt_pk_bf16(float lo, float hi){
  unsigned r;
  asm("v_cvt_pk_bf16_f32 %0, %1, %2" : "=v"(r) : "v"(lo), "v"(hi));
  return r;
}

// ---------------- K1: prep (fused) ----------------
// blocks 0..127 : fragment-major bf16 Wr:
//   frag f = (t16*16 + kt)*64 + lane holds Wr[t16*16+(lane&15)][kt*32+(lane>>4)*8 ..+8]
//   -> k_main B-frag load = ONE contiguous 1KB wave load.
// blocks 128..159: qb[b,h] = bq[h] + br[h] + query[b,:] . Wq[h,:]
__global__ __launch_bounds__(256) void k_prep(const float* __restrict__ Wr,
                                              unsigned short* __restrict__ wrbF,
                                              const float* __restrict__ query,
                                              const float* __restrict__ Wq,
                                              const float* __restrict__ bq,
                                              const float* __restrict__ br,
                                              float* __restrict__ qb){
  int t = threadIdx.x;
  if (blockIdx.x < 128){
    int gid = blockIdx.x*256 + t;        // [0, 32768)
    int lane = gid & 63;
    int tile = gid >> 6;                 // [0,512): kt = tile&15, t16 = tile>>4
    int kt = tile & 15, t16 = tile >> 4;
    int col = t16*16 + (lane & 15);
    int k0  = kt*32 + (lane >> 4)*8;
    const float* src = Wr + (size_t)col*HDIM + k0;
    f32x4 v0 = *(const f32x4*)(src);
    f32x4 v1 = *(const f32x4*)(src + 4);
    uint4 o;
    o.x = cvt_pk_bf16(v0.x, v0.y);
    o.y = cvt_pk_bf16(v0.z, v0.w);
    o.z = cvt_pk_bf16(v1.x, v1.y);
    o.w = cvt_pk_bf16(v1.z, v1.w);
    *(uint4*)(wrbF + (size_t)gid*8) = o;
  } else {
    __shared__ __align__(16) float sq[HDIM];
    int b = blockIdx.x - 128;
    sq[t] = query[b*HDIM + t];
    sq[t+256] = query[b*HDIM + t + 256];
    __syncthreads();
    const f32x4* sq4 = (const f32x4*)sq;
    for (int hh = 0; hh < 2; ++hh){
      int h = t + hh*256;
      const f32x4* w4 = (const f32x4*)(Wq + (size_t)h*HDIM);
      float acc = bq[h] + br[h];
      #pragma unroll 4
      for (int k = 0; k < HDIM/4; ++k){
        f32x4 w = w4[k]; f32x4 q = sq4[k];
        acc += w.x*q.x + w.y*q.y + w.z*q.z + w.w*q.w;
      }
      qb[b*HDIM + h] = acc;
    }
  }
}

// ---------------- K2: main fused kernel ----------------
// 2048 blocks x 512 thr (8 waves), 64-row tile, ~70KB LDS -> 2 blocks/CU.
// Single-pass GEMM: wave covers cols [w*64, w*64+64) with acc[4][4] -> A tile
// read ONCE per wave. A ds_reads use two uniform bases (R7 identity):
//   (kt*64+g*16)^((row&7)<<4) = (kt^b)*64 + (g*16^((row&3)<<4)), b=(row>>2)&1.
// Output partial computed in r-domain from in-register acc (no u-pass):
//   prb[col] = sum_rows e_row * acc ; out = sc-combine(prb) + br in k_final.
__global__ __launch_bounds__(512)
__attribute__((amdgpu_waves_per_eu(4, 4)))
void k_main(const float* __restrict__ ref,
            const unsigned short* __restrict__ wrbF,
            const float* __restrict__ qb,
            const float* __restrict__ V,
            float* __restrict__ pm,
            float* __restrict__ pd,
            float* __restrict__ prb){
  int bid = blockIdx.x;
  int b = bid >> 6;
  int chunk = bid & 63;
  int tid = threadIdx.x;
  int w = tid >> 6, lane = tid & 63;
  int lo16 = lane & 15, g = lane >> 4;

  __shared__ __align__(16) unsigned short sA[TR*HDIM]; // 64KB swizzled bf16
  __shared__ __align__(16) float sQb[HDIM];
  __shared__ __align__(16) float sV[HDIM];
  __shared__ float sLog[8][TR];
  __shared__ __align__(16) float sE[TR];

  sQb[tid] = qb[b*HDIM + tid];
  sV[tid]  = V[tid];

  // ---- stage A: 64 rows x 512 f32 = 8192 f32x4; two half-passes of 8/thread ----
  {
    const f32x4* s4 = (const f32x4*)(ref + ((size_t)b*SS + (size_t)chunk*TR)*HDIM) + tid;
    #pragma unroll
    for (int p = 0; p < 2; ++p){
      f32x4 R[8];
      #pragma unroll
      for (int i = 0; i < 8; ++i) R[i] = s4[p*4096 + 512*i];
      #pragma unroll
      for (int i = 0; i < 8; ++i){
        int idx = tid + 512*i + p*4096;
        int row = idx >> 7, c4 = idx & 127;
        f32x4 v = R[i];
        uint2 o;
        o.x = cvt_pk_bf16(v.x, v.y);
        o.y = cvt_pk_bf16(v.z, v.w);
        unsigned byte = (unsigned)(row*1024) + (((unsigned)c4*8) ^ ((unsigned)(row & 7) << 4));
        *(uint2*)((char*)sA + byte) = o;
      }
    }
  }
  __syncthreads();

  // ---- GEMM: single pass, wave cols [w*64, w*64+64), rows 0..63 ----
  unsigned baseA = (unsigned)(lo16*1024) + (((unsigned)g*16) ^ ((unsigned)(lo16 & 3) << 4));
  unsigned bsel  = (unsigned)((lo16 >> 2) & 1) * 64u;
  const char* pAe = (const char*)sA + baseA + bsel;        // even kt: + kt*64
  const char* pAo = (const char*)sA + baseA - bsel + 64;   // odd kt:  + (kt-1)*64
  const short8* wfp = (const short8*)wrbF + ((size_t)(w*4)*16*64 + lane);

  f32x4 acc[4][4];
  #pragma unroll
  for (int m = 0; m < 4; ++m)
    #pragma unroll
    for (int n = 0; n < 4; ++n)
      acc[m][n] = (f32x4){0.f, 0.f, 0.f, 0.f};

  #pragma unroll 4
  for (int kt = 0; kt < 16; ++kt){
    short8 af[4];
    #pragma unroll
    for (int m = 0; m < 4; ++m){
      if (kt & 1)
        af[m] = *(const short8*)(pAo + (m*16384 + (kt-1)*64));
      else
        af[m] = *(const short8*)(pAe + (m*16384 + kt*64));
    }
    short8 bfr[4];
    #pragma unroll
    for (int n = 0; n < 4; ++n)
      bfr[n] = wfp[(size_t)n*1024 + kt*64];
    #pragma unroll
    for (int m = 0; m < 4; ++m)
      #pragma unroll
      for (int n = 0; n < 4; ++n)
        acc[m][n] = __builtin_amdgcn_mfma_f32_16x16x32_bf16(af[m], bfr[n], acc[m][n], 0, 0, 0);
  }

  // ---- logits epilogue: D-layout col=w*64+n*16+(lane&15), row=16m+4g+r ----
  // per elem: vv - 2*vv*rcp(1+exp2(C*x)), x = qb+acc  (qb folds bq+br)
  const float C2L2E = 2.8853900817779268f;   // 2*log2(e)
  float lacc[4][4];
  #pragma unroll
  for (int m = 0; m < 4; ++m)
    #pragma unroll
    for (int r = 0; r < 4; ++r)
      lacc[m][r] = 0.f;
  float SV = 0.f;

  #pragma unroll
  for (int n = 0; n < 4; ++n){
    int col = w*64 + n*16 + lo16;
    float qc  = C2L2E * sQb[col];
    float vv  = sV[col];
    float vv2 = -2.f * vv;
    SV += vv;
    #pragma unroll
    for (int m = 0; m < 4; ++m)
      #pragma unroll
      for (int r = 0; r < 4; ++r){
        float e  = __builtin_amdgcn_exp2f(__builtin_fmaf(C2L2E, acc[m][n][r], qc));
        float rc = __builtin_amdgcn_rcpf(1.f + e);
        lacc[m][r] = __builtin_fmaf(vv2, rc, lacc[m][r]);
      }
  }
  #pragma unroll
  for (int m = 0; m < 4; ++m)
    #pragma unroll
    for (int r = 0; r < 4; ++r)
      lacc[m][r] += SV;

  // reduce over 16 lanes (cols) -> logit partials for rows 16m+4g+r
  #pragma unroll
  for (int m = 0; m < 4; ++m)
    #pragma unroll
    for (int r = 0; r < 4; ++r){
      float v = lacc[m][r];
      v += __shfl_xor(v, 1); v += __shfl_xor(v, 2);
      v += __shfl_xor(v, 4); v += __shfl_xor(v, 8);
      lacc[m][r] = v;
    }
  if (lo16 == 0){
    #pragma unroll
    for (int m = 0; m < 4; ++m)
      #pragma unroll
      for (int r = 0; r < 4; ++r)
        sLog[w][16*m + 4*g + r] = lacc[m][r];
  }
  __syncthreads();

  // ---- chunk softmax partials (wave 0; 64 lanes = 64 rows) ----
  if (w == 0){
    float l = sLog[0][lane] + sLog[1][lane] + sLog[2][lane] + sLog[3][lane]
            + sLog[4][lane] + sLog[5][lane] + sLog[6][lane] + sLog[7][lane];
    float mx = l;
    mx = fmaxf(mx, __shfl_xor(mx, 1));  mx = fmaxf(mx, __shfl_xor(mx, 2));
    mx = fmaxf(mx, __shfl_xor(mx, 4));  mx = fmaxf(mx, __shfl_xor(mx, 8));
    mx = fmaxf(mx, __shfl_xor(mx, 16)); mx = fmaxf(mx, __shfl_xor(mx, 32));
    float e = __expf(l - mx);
    float d = e;
    d += __shfl_xor(d, 1); d += __shfl_xor(d, 2); d += __shfl_xor(d, 4);
    d += __shfl_xor(d, 8); d += __shfl_xor(d, 16); d += __shfl_xor(d, 32);
    sE[lane] = e;
    if (lane == 0){ pm[bid] = mx; pd[bid] = d; }
  }
  __syncthreads();

  // ---- r-domain partial from in-register acc: prb[col] = sum_rows e*acc ----
  {
    f32x4 e4[4];
    #pragma unroll
    for (int m = 0; m < 4; ++m)
      e4[m] = *(const f32x4*)&sE[16*m + 4*g];     // rows 16m+4g+0..3
    #pragma unroll
    for (int n = 0; n < 4; ++n){
      float rb = 0.f;
      #pragma unroll
      for (int m = 0; m < 4; ++m)
        #pragma unroll
        for (int r = 0; r < 4; ++r)
          rb = __builtin_fmaf(e4[m][r], acc[m][n][r], rb);
      rb += __shfl_xor(rb, 16);
      rb += __shfl_xor(rb, 32);     // fold the 4 g-groups (rows)
      if (g == 0)
        prb[(size_t)bid*HDIM + w*64 + n*16 + lo16] = rb;
    }
  }
}

// ---------------- K3: combine 64 r-domain partials per b, add br ----------------
__global__ __launch_bounds__(256) void k_final(const float* __restrict__ br,
                                               const float* __restrict__ pm,
                                               const float* __restrict__ pd,
                                               const float* __restrict__ prb,
                                               float* __restrict__ out){
  int b = blockIdx.x, t = threadIdx.x, lane = t & 63, w = t >> 6;
  __shared__ float sSc[NCH];
  __shared__ float sMD0;

  if (w == 0){
    float m = pm[b*NCH + lane];
    float mx = m;
    mx = fmaxf(mx, __shfl_xor(mx, 1));  mx = fmaxf(mx, __shfl_xor(mx, 2));
    mx = fmaxf(mx, __shfl_xor(mx, 4));  mx = fmaxf(mx, __shfl_xor(mx, 8));
    mx = fmaxf(mx, __shfl_xor(mx, 16)); mx = fmaxf(mx, __shfl_xor(mx, 32));
    float sc = __expf(m - mx);
    float d = sc * pd[b*NCH + lane];
    d += __shfl_xor(d, 1); d += __shfl_xor(d, 2); d += __shfl_xor(d, 4);
    d += __shfl_xor(d, 8); d += __shfl_xor(d, 16); d += __shfl_xor(d, 32);
    sSc[lane] = sc;
    if (lane == 0) sMD0 = d;
  }
  __syncthreads();

  float inv = 1.f / sMD0;
  float u0 = 0.f, u1 = 0.f;
  for (int c = 0; c < NCH; ++c){
    float sc = sSc[c];
    const float* p = prb + ((size_t)(b*NCH + c))*HDIM;
    u0 += sc * p[t];
    u1 += sc * p[t+256];
  }
  out[b*HDIM + t]       = u0 * inv + br[t];
  out[b*HDIM + t + 256] = u1 * inv + br[t + 256];
}

extern "C" void kernel_launch(void* const* d_in, const int* in_sizes, int n_in,
                              void* d_out, int out_size, void* d_ws, size_t ws_size,
                              hipStream_t stream){
  const float* query = (const float*)d_in[0];
  const float* ref   = (const float*)d_in[1];
  const float* Wq    = (const float*)d_in[2];
  const float* bq    = (const float*)d_in[3];
  const float* Wr    = (const float*)d_in[4];
  const float* br    = (const float*)d_in[5];
  const float* V     = (const float*)d_in[6];
  char* ws = (char*)d_ws;
  float*          qbv  = (float*)(ws + WS_QB);
  unsigned short* wrbF = (unsigned short*)(ws + WS_WRBF);
  float*          pm   = (float*)(ws + WS_PM);
  float*          pd   = (float*)(ws + WS_PD);
  float*          prb  = (float*)(ws + WS_PRB);
  float* out = (float*)d_out;

  k_prep<<<dim3(160), dim3(256), 0, stream>>>(Wr, wrbF, query, Wq, bq, br, qbv);
  k_main<<<dim3(NBLK), dim3(512), 0, stream>>>(ref, wrbF, qbv, V, pm, pd, prb);
  k_final<<<dim3(BB), dim3(256), 0, stream>>>(br, pm, pd, prb, out);
}